// Round 1
// 116.342 us; speedup vs baseline: 1.1095x; 1.1095x over previous
//
#include <hip/hip_runtime.h>
#include <math.h>

#define B_ROWS 8192
#define NU 512
#define FEATS 64
#define RPB 8      // rows per block (= waves per block)
#define TOPK_K 8

typedef unsigned long long ull;

// xor-1 / xor-2 lane exchange via DPP quad_perm (VALU pipe, no DS)
template <int CTRL>
__device__ __forceinline__ ull dpp_u64(ull x) {
  int lo = (int)(unsigned)(x & 0xffffffffULL);
  int hi = (int)(unsigned)(x >> 32);
  lo = __builtin_amdgcn_update_dpp(lo, lo, CTRL, 0xf, 0xf, true);
  hi = __builtin_amdgcn_update_dpp(hi, hi, CTRL, 0xf, 0xf, true);
  return ((ull)(unsigned)hi << 32) | (ull)(unsigned)lo;
}

__device__ __forceinline__ ull bperm_u64(int addr, ull x) {
  int lo = (int)(unsigned)(x & 0xffffffffULL);
  int hi = (int)(unsigned)(x >> 32);
  lo = __builtin_amdgcn_ds_bpermute(addr, lo);
  hi = __builtin_amdgcn_ds_bpermute(addr, hi);
  return ((ull)(unsigned)hi << 32) | (ull)(unsigned)lo;
}

// compare-exchange: after call, (a,b) ordered ascending iff asc
__device__ __forceinline__ void ce(ull& a, ull& b, bool asc) {
  const bool lt = a < b;
  const bool sw = (lt != asc);
  const ull t = sw ? b : a;
  b = sw ? a : b;
  a = t;
}

// cross-lane pass: lane-xor M, merge-size direction bit KB = K>>3
template <unsigned M, unsigned KB>
__device__ __forceinline__ void cross_t(ull v[8], unsigned lane, int addr) {
  const bool asc = ((lane & KB) == 0u);
  const bool takeMin = (((lane & M) == 0u) == asc);
#pragma unroll
  for (int i = 0; i < 8; ++i) {
    ull o;
    if constexpr (M == 1)      o = dpp_u64<0xB1>(v[i]);   // quad_perm [1,0,3,2]
    else if constexpr (M == 2) o = dpp_u64<0x4E>(v[i]);   // quad_perm [2,3,0,1]
    else                       o = bperm_u64(addr, v[i]);
    const bool keep = ((v[i] < o) == takeMin);
    v[i] = keep ? v[i] : o;
  }
}

// one bitonic merge stage of size K (16..512), fully compile-time unrolled
template <unsigned K>
__device__ __forceinline__ void stage_t(ull v[8], unsigned lane,
                                        int a4, int a8, int a16, int a32) {
  constexpr unsigned KB = (K >> 3);
  if constexpr (K >= 512) cross_t<32, KB>(v, lane, a32);
  if constexpr (K >= 256) cross_t<16, KB>(v, lane, a16);
  if constexpr (K >= 128) cross_t<8,  KB>(v, lane, a8);
  if constexpr (K >= 64)  cross_t<4,  KB>(v, lane, a4);
  if constexpr (K >= 32)  cross_t<2,  KB>(v, lane, 0);
  cross_t<1, KB>(v, lane, 0);
  const bool asc = ((lane & KB) == 0u);
  ce(v[0], v[4], asc); ce(v[1], v[5], asc); ce(v[2], v[6], asc); ce(v[3], v[7], asc);
  ce(v[0], v[2], asc); ce(v[1], v[3], asc); ce(v[4], v[6], asc); ce(v[5], v[7], asc);
  ce(v[0], v[1], asc); ce(v[2], v[3], asc); ce(v[4], v[5], asc); ce(v[6], v[7], asc);
}

__global__ __launch_bounds__(512)
void lcm_kernel(const float* __restrict__ x, const float* __restrict__ c,
                float* __restrict__ out) {
#pragma clang fp contract(off)
  __shared__ ull keys[RPB * NU];            // 32 KB
  __shared__ unsigned short rks[RPB * NU];  // 8 KB  (total 40 KB -> still 4 blocks/CU)

  const int t = threadIdx.x;
  const int r0 = blockIdx.x * RPB;

  // ---- distances: XLA-CPU AVX-512-style reduce, bitwise identical to r6 ----
  {
    const int n = t;
    float4 cs4[16];
    const float4* c4 = (const float4*)c + (size_t)n * 16;
#pragma unroll
    for (int q = 0; q < 16; ++q) cs4[q] = c4[q];

    float* o_d = out;
#pragma unroll
    for (int r = 0; r < RPB; ++r) {
      const float* __restrict__ xr = x + (size_t)(r0 + r) * FEATS;  // uniform
      float rr[16];
#pragma unroll
      for (int k = 0; k < 4; ++k) {
        const float4 xq0 = *(const float4*)(xr + 16 * k + 0);
        const float4 xq1 = *(const float4*)(xr + 16 * k + 4);
        const float4 xq2 = *(const float4*)(xr + 16 * k + 8);
        const float4 xq3 = *(const float4*)(xr + 16 * k + 12);
        const float4 xq[4] = {xq0, xq1, xq2, xq3};
#pragma unroll
        for (int q = 0; q < 4; ++q) {
          const float4 cv = cs4[k * 4 + q];
          const float4 xv = xq[q];
          const float t0 = xv.x - cv.x;
          const float t1 = xv.y - cv.y;
          const float t2 = xv.z - cv.z;
          const float t3 = xv.w - cv.w;
          if (k == 0) {
            rr[q * 4 + 0] = t0 * t0;
            rr[q * 4 + 1] = t1 * t1;
            rr[q * 4 + 2] = t2 * t2;
            rr[q * 4 + 3] = t3 * t3;
          } else {
            rr[q * 4 + 0] = rr[q * 4 + 0] + t0 * t0;
            rr[q * 4 + 1] = rr[q * 4 + 1] + t1 * t1;
            rr[q * 4 + 2] = rr[q * 4 + 2] + t2 * t2;
            rr[q * 4 + 3] = rr[q * 4 + 3] + t3 * t3;
          }
        }
      }
      float s8[8], s4[4], s2[2];
#pragma unroll
      for (int j = 0; j < 8; ++j) s8[j] = rr[j] + rr[j + 8];
#pragma unroll
      for (int j = 0; j < 4; ++j) s4[j] = s8[j] + s8[j + 4];
#pragma unroll
      for (int j = 0; j < 2; ++j) s2[j] = s4[j] + s4[j + 2];
      const float tot = s2[0] + s2[1];
      const float dv = (float)__builtin_sqrt((double)tot);
      o_d[(size_t)(r0 + r) * NU + n] = dv;
      keys[r * NU + n] = ((ull)__float_as_uint(dv) << 32) | (ull)n;
    }
  }
  __syncthreads();

  // ---- per-wave stable bitonic sort of 512 keys (wave w = row w) ----
  {
    const unsigned lane = (unsigned)(t & 63);
    const int w = t >> 6;

    ull v[8];
#pragma unroll
    for (int i = 0; i < 8; ++i) v[i] = keys[w * NU + i * 64 + (int)lane];

    // pre-stages K=2,4,8 (directions compile-time / lane-bit0)
    ce(v[0], v[1], true);  ce(v[2], v[3], false);
    ce(v[4], v[5], true);  ce(v[6], v[7], false);            // K=2
    ce(v[0], v[2], true);  ce(v[1], v[3], true);
    ce(v[4], v[6], false); ce(v[5], v[7], false);            // K=4 S=2
    ce(v[0], v[1], true);  ce(v[2], v[3], true);
    ce(v[4], v[5], false); ce(v[6], v[7], false);            // K=4 S=1
    {
      const bool a8 = ((lane & 1u) == 0u);                   // K=8
      ce(v[0], v[4], a8); ce(v[1], v[5], a8); ce(v[2], v[6], a8); ce(v[3], v[7], a8);
      ce(v[0], v[2], a8); ce(v[1], v[3], a8); ce(v[4], v[6], a8); ce(v[5], v[7], a8);
      ce(v[0], v[1], a8); ce(v[2], v[3], a8); ce(v[4], v[5], a8); ce(v[6], v[7], a8);
    }

    const int ad4  = (int)((lane ^ 4u)  << 2);
    const int ad8  = (int)((lane ^ 8u)  << 2);
    const int ad16 = (int)((lane ^ 16u) << 2);
    const int ad32 = (int)((lane ^ 32u) << 2);
    stage_t<16>(v, lane, ad4, ad8, ad16, ad32);
    stage_t<32>(v, lane, ad4, ad8, ad16, ad32);
    stage_t<64>(v, lane, ad4, ad8, ad16, ad32);
    stage_t<128>(v, lane, ad4, ad8, ad16, ad32);
    stage_t<256>(v, lane, ad4, ad8, ad16, ad32);
    stage_t<512>(v, lane, ad4, ad8, ad16, ad32);

    const int row = r0 + w;
    float* o_is = out + (size_t)B_ROWS * NU;
    float* o_k  = o_is + (size_t)B_ROWS * NU;
    float* o_z  = o_k + (size_t)B_ROWS * NU;
    float* o_xc = o_z + (size_t)B_ROWS * NU;

    int idxv[8];
#pragma unroll
    for (int i = 0; i < 8; ++i) idxv[i] = (int)(v[i] & 0x1ffULL);

    // i_sort: coalesced float4 stores (unchanged)
    float4 fa, fb;
    fa.x = (float)idxv[0]; fa.y = (float)idxv[1];
    fa.z = (float)idxv[2]; fa.w = (float)idxv[3];
    fb.x = (float)idxv[4]; fb.y = (float)idxv[5];
    fb.z = (float)idxv[6]; fb.w = (float)idxv[7];
    float4* isrow = (float4*)(o_is + (size_t)row * NU);
    isrow[lane * 2 + 0] = fa;
    isrow[lane * 2 + 1] = fb;

    // ---- inverse permutation in LDS (wave-private row), then coalesced k/z ----
    // rank of original index idxv[i] is e = lane*8 + i
#pragma unroll
    for (int i = 0; i < 8; ++i)
      rks[w * NU + idxv[i]] = (unsigned short)((int)lane * 8 + i);

    // lane l (l<8) holds zval = 1/(l+1); recovered per-element via bpermute.
    // Constants fold identically to 1.0f/(float)(i+1) (IEEE round-to-nearest).
    const unsigned l8 = lane & 7u;
    const float v00 = (l8 & 1u) ? 0.5f : 1.0f;
    const float v01 = (l8 & 1u) ? 0.25f : (1.0f / 3.0f);
    const float v10 = (l8 & 1u) ? (1.0f / 6.0f) : 0.2f;
    const float v11 = (l8 & 1u) ? 0.125f : (1.0f / 7.0f);
    const float va  = (l8 & 2u) ? v01 : v00;
    const float vb  = (l8 & 2u) ? v11 : v10;
    const float zv  = (l8 & 4u) ? vb : va;

#pragma unroll
    for (int j = 0; j < 8; ++j) {
      const int e = (int)rks[w * NU + j * 64 + (int)lane];   // ds_read_u16, conflict-free
      const int zb = __builtin_amdgcn_ds_bpermute((e & 63) << 2, __float_as_int(zv));
      const float ze = (e < TOPK_K) ? __int_as_float(zb) : 0.0f;
      o_k[(size_t)row * NU + j * 64 + (int)lane] = (float)e;  // coalesced
      o_z[(size_t)row * NU + j * 64 + (int)lane] = ze;        // coalesced
    }

    int top = idxv[0];
    top = __shfl(top, 0, 64);
    o_xc[(size_t)row * FEATS + (int)lane] = c[top * FEATS + (int)lane];
  }
}

extern "C" void kernel_launch(void* const* d_in, const int* in_sizes, int n_in,
                              void* d_out, int out_size, void* d_ws, size_t ws_size,
                              hipStream_t stream) {
  const float* x = (const float*)d_in[0];
  const float* c = (const float*)d_in[1];
  float* out = (float*)d_out;
  lcm_kernel<<<dim3(B_ROWS / RPB), dim3(512), 0, stream>>>(x, c, out);
}